// Round 11
// baseline (2611.098 us; speedup 1.0000x reference)
//
#include <hip/hip_runtime.h>
#include <hip/hip_bf16.h>
#include <cstdint>
#include <cstddef>

// LRU forward: B=16, T=4096, IN=OUT=N=512
// prep weights (bf16, perm layout) -> convert u -> GEMM1 (Bu; 256^2, B-in-regs,
// A-only LDS 64KB, 2 blocks/CU) -> scan_carry -> prefix -> apply -> GEMM2.
// d_out doubles as scratch for Bu before y overwrites it.
//
// Perm layout: row-major rows; each 64-k tile is 128 B = 8 chunks of 16 B.
// Chunk c at row r holds fragment chunk cc = c ^ (r&7); fragment chunk
// cc = kk*4+g holds k = {kk*32+g*4+j, kk*32+16+g*4+j}. One ds_read_b128 (A via
// LDS) or one global_load_dwordx4 (B direct from L2) = one MFMA fragment.
//
// K-loop: B fragments prefetched to registers one tile ahead (banked via 2x
// unroll); DS traffic is A-only (16 reads/wave-tile); one vmcnt(0)+barrier per
// tile with the round-9-verified tail (reg-only MFMAs BEFORE the barrier).

using short8 = __attribute__((ext_vector_type(8))) short;
using f32x4 = __attribute__((ext_vector_type(4))) float;

#define BDIM 16
#define TDIM 4096
#define MTOT (BDIM * TDIM)   // 65536
#define CHUNK 64
#define NCHUNK (TDIM / CHUNK) // 64

__device__ __forceinline__ unsigned short f2bf(float f) {
    unsigned u = __float_as_uint(f);
    u = u + 0x7FFFu + ((u >> 16) & 1u);   // RNE
    return (unsigned short)(u >> 16);
}
__device__ __forceinline__ float bflo(unsigned w) { return __uint_as_float(w << 16); }
__device__ __forceinline__ float bfhi(unsigned w) { return __uint_as_float(w & 0xFFFF0000u); }

__device__ __forceinline__ size_t perm_off(int row, int kt, int kp, int rowbytes) {
    int kk = kp >> 5, km = kp & 31;
    int half = km >> 4;
    int g = (km & 15) >> 2, j = km & 3;
    int cc = (kk << 2) | g;
    int c = cc ^ (row & 7);
    return (size_t)row * rowbytes + kt * 128 + (c << 4) + half * 8 + j * 2;
}

__device__ __forceinline__ void gload_lds16(const void* g, void* l) {
    __builtin_amdgcn_global_load_lds((const __attribute__((address_space(1))) void*)g,
                                     (__attribute__((address_space(3))) void*)l, 16, 0, 0);
}

// ---------------- weight prep ----------------
__global__ void prep_w1(const float* __restrict__ B_re, const float* __restrict__ B_im,
                        const float* __restrict__ gamma_log, char* __restrict__ W1) {
    int i = blockIdx.x * 256 + threadIdx.x;  // 0..511 (k)
    int r = blockIdx.y;                      // 0..1023 (row)
    int n = r >> 1;
    float gmm = expf(gamma_log[n]);
    float v = (r & 1) ? B_im[n * 512 + i] * gmm : B_re[n * 512 + i] * gmm;
    *(unsigned short*)(W1 + perm_off(r, i >> 6, i & 63, 1024)) = f2bf(v);
}

__global__ void prep_w2(const float* __restrict__ C_re, const float* __restrict__ C_im,
                        const float* __restrict__ D, char* __restrict__ W2) {
    int k = blockIdx.x * 256 + threadIdx.x;  // 0..1535
    int o = blockIdx.y;                      // 0..511
    float v;
    if (k < 1024) {
        int n = k >> 1;
        v = (k & 1) ? -2.0f * C_im[o * 512 + n] : 2.0f * C_re[o * 512 + n];
    } else {
        v = D[o * 512 + (k - 1024)];
    }
    *(unsigned short*)(W2 + perm_off(o, k >> 6, k & 63, 3072)) = f2bf(v);
}

__global__ void convert_u(const float4* __restrict__ u4, char* __restrict__ Apack) {
    size_t idx = (size_t)blockIdx.x * 256 + threadIdx.x;  // < 65536*128
    float4 v = u4[idx];
    int row = (int)(idx >> 7);
    int c4 = (int)(idx & 127);
    int kg = 1024 + c4 * 4;
    unsigned lo = (unsigned)f2bf(v.x) | ((unsigned)f2bf(v.y) << 16);
    unsigned hi = (unsigned)f2bf(v.z) | ((unsigned)f2bf(v.w) << 16);
    size_t off = perm_off(row, kg >> 6, kg & 63, 3072);
    *reinterpret_cast<uint2*>(Apack + off) = make_uint2(lo, hi);
}

// ---------------- 256x256 MFMA GEMM, B-in-regs, A-only LDS ----------------
#define ASM_VMCNT0 asm volatile("s_waitcnt vmcnt(0)" ::: "memory")
#define ASM_LGKM0  asm volatile("s_waitcnt lgkmcnt(0)" ::: "memory")
#define ASM_LGKM4  asm volatile("s_waitcnt lgkmcnt(4)" ::: "memory")
#define SCHED0     __builtin_amdgcn_sched_barrier(0)
#define BARRIER    __builtin_amdgcn_s_barrier()
#define PRIO1      __builtin_amdgcn_s_setprio(1)
#define PRIO0      __builtin_amdgcn_s_setprio(0)

template <int OUT_MODE, int NBN, int LDAB, int LDBB>
__global__ __launch_bounds__(512, 4) void gemm_nt(const char* __restrict__ A,
                                                  const char* __restrict__ Bm,
                                                  void* __restrict__ Cout, int ktiles) {
    __shared__ __align__(16) char lds[65536];   // A double buffer: 2 x 32 KB
    const int tid = threadIdx.x;
    const int lane = tid & 63, w = tid >> 6;
    const int bid = blockIdx.x;
    const int cpx = gridDim.x >> 3;             // grid divisible by 8
    const int swz = (bid & 7) * cpx + (bid >> 3);
    const int bm = swz / NBN, bn = swz % NBN;
    const int wm = (w >> 2) * 128, wn = (w & 3) * 64;
    const int ml = lane & 15, g = lane >> 4;

    const char* AgrL = A + (size_t)(bm * 256 + w * 16 + (lane >> 3)) * LDAB + (lane & 7) * 16;

#define STG_A(h, kt_, q) do {                                                         \
        const char* s_ = AgrL + (size_t)((h) * 128) * LDAB + (size_t)(kt_) * 128;     \
        char* d_ = lds + (q) * 32768 + (h) * 16384 + w * 2048;                        \
        gload_lds16(s_, d_);                                                          \
        gload_lds16(s_ + (size_t)8 * LDAB, d_ + 1024);                                \
    } while (0)

    // B fragment direct from global (L2-resident weights), perm layout = one 16B chunk
#define LOADB(BNK, kt_) do {                                                          \
        _Pragma("unroll") for (int nh = 0; nh < 2; ++nh)                              \
        _Pragma("unroll") for (int ntq = 0; ntq < 2; ++ntq)                           \
        _Pragma("unroll") for (int kk = 0; kk < 2; ++kk) {                            \
            int c_ = bn * 256 + wn + nh * 32 + ntq * 16 + ml;                         \
            BNK[nh][ntq][kk] = *reinterpret_cast<const short8*>(                      \
                Bm + (size_t)c_ * LDBB + (size_t)(kt_) * 128 +                        \
                ((((kk << 2) | g) ^ (ml & 7)) << 4));                                 \
        } } while (0)

#define RD_A1(mh, mt_, Abase) do {                                                    \
        _Pragma("unroll") for (int kk = 0; kk < 2; ++kk) {                            \
            int r_ = wm + (mh) * 64 + (mt_) * 16 + ml;                                \
            int hf_ = r_ >> 7, rl_ = r_ & 127;                                        \
            afr[mt_][kk] = *reinterpret_cast<const short8*>(                          \
                (Abase) + hf_ * 16384 + rl_ * 128 + ((((kk << 2) | g) ^ (rl_ & 7)) << 4)); \
        } } while (0)

#define MFMA8_MT(mh, mtb, nh, BNK)                                                    \
    _Pragma("unroll") for (int kk = 0; kk < 2; ++kk)                                  \
    _Pragma("unroll") for (int mi = 0; mi < 2; ++mi)                                  \
    _Pragma("unroll") for (int nt = 0; nt < 2; ++nt)                                  \
        acc[(mh) * 4 + (mtb) + mi][(nh) * 2 + nt] = __builtin_amdgcn_mfma_f32_16x16x32_bf16( \
            afr[(mtb) + mi][kk], BNK[nh][nt][kk], acc[(mh) * 4 + (mtb) + mi][(nh) * 2 + nt], 0, 0, 0)
#define MFMA8_NT(mh, nh, ntq, BNK)                                                    \
    _Pragma("unroll") for (int kk = 0; kk < 2; ++kk)                                  \
    _Pragma("unroll") for (int mt = 0; mt < 4; ++mt)                                  \
        acc[(mh) * 4 + mt][(nh) * 2 + (ntq)] = __builtin_amdgcn_mfma_f32_16x16x32_bf16( \
            afr[mt][kk], BNK[nh][ntq][kk], acc[(mh) * 4 + mt][(nh) * 2 + (ntq)], 0, 0, 0)

#define TILE(kt_, CURB, NXTB, q, nq) do {                                             \
        const bool more_ = ((kt_) + 1 < ktiles);                                      \
        const char* Ab_ = lds + (q) * 32768;                                          \
        if (more_) {                                                                  \
            LOADB(NXTB, (kt_) + 1);                                                   \
            STG_A(0, (kt_) + 1, nq); STG_A(1, (kt_) + 1, nq);                         \
        }                                                                             \
        RD_A1(0, 0, Ab_); RD_A1(0, 1, Ab_);                                           \
        SCHED0;                                                                       \
        RD_A1(0, 2, Ab_); RD_A1(0, 3, Ab_);                                           \
        ASM_LGKM4; SCHED0;                                                            \
        PRIO1; MFMA8_MT(0, 0, 0, CURB); PRIO0;                                        \
        ASM_LGKM0; SCHED0;                                                            \
        PRIO1; MFMA8_MT(0, 2, 0, CURB); PRIO0;                                        \
        PRIO1; MFMA8_NT(0, 1, 0, CURB); MFMA8_NT(0, 1, 1, CURB); PRIO0;               \
        RD_A1(1, 0, Ab_); RD_A1(1, 1, Ab_);                                           \
        SCHED0;                                                                       \
        RD_A1(1, 2, Ab_); RD_A1(1, 3, Ab_);                                           \
        ASM_LGKM4; SCHED0;                                                            \
        PRIO1; MFMA8_MT(1, 0, 0, CURB); PRIO0;                                        \
        ASM_LGKM0; SCHED0;                                                            \
        PRIO1; MFMA8_MT(1, 2, 0, CURB); PRIO0;                                        \
        PRIO1; MFMA8_MT(1, 0, 1, CURB); MFMA8_MT(1, 2, 1, CURB); PRIO0;               \
        ASM_VMCNT0;                                                                   \
        BARRIER;                                                                      \
        SCHED0;                                                                       \
    } while (0)

    f32x4 acc[8][4] = {};
    short8 afr[4][2];
    short8 bA[2][2][2], bB[2][2][2];

    // prologue: B[0] -> regs, A[0] -> buf0
    LOADB(bA, 0);
    STG_A(0, 0, 0); STG_A(1, 0, 0);
    ASM_VMCNT0;
    BARRIER;
    SCHED0;

    const int NT = ktiles >> 1;
    for (int it = 0; it < NT; ++it) {
        TILE(2 * it,     bA, bB, 0, 1);
        TILE(2 * it + 1, bB, bA, 1, 0);
    }

    // ---------------- epilogue ----------------
    if (OUT_MODE == 0) {
        float* O = (float*)Cout;
#pragma unroll
        for (int mt = 0; mt < 8; ++mt)
#pragma unroll
            for (int nt = 0; nt < 4; ++nt)
#pragma unroll
                for (int r_ = 0; r_ < 4; ++r_) {
                    int grow = bm * 256 + wm + mt * 16 + g * 4 + r_;
                    int gcol = bn * 256 + wn + nt * 16 + ml;
                    O[(size_t)grow * 512 + gcol] = acc[mt][nt][r_];
                }
    } else {
        unsigned short* BuOut = (unsigned short*)Cout;
#pragma unroll
        for (int mt = 0; mt < 8; ++mt)
#pragma unroll
            for (int nt = 0; nt < 4; ++nt)
#pragma unroll
                for (int r_ = 0; r_ < 4; ++r_) {
                    int lrow = wm + mt * 16 + g * 4 + r_;
                    int lcol = wn + nt * 16 + ml;
                    BuOut[(size_t)(bm * 256 + lrow) * 1024 + bn * 256 + lcol] =
                        f2bf(acc[mt][nt][r_]);
                }
    }
#undef STG_A
#undef LOADB
#undef RD_A1
#undef MFMA8_MT
#undef MFMA8_NT
#undef TILE
}

// ---------------- scan ----------------
__global__ void scan_carry(const unsigned* __restrict__ Bu, const float* __restrict__ nu_log,
                           const float* __restrict__ theta_log, float2* __restrict__ carry) {
    int q = blockIdx.x * 256 + threadIdx.x;  // < 16*64*512
    int n = q & 511, c = (q >> 9) & 63, b = q >> 15;
    float mod = expf(-expf(nu_log[n]));
    float th = expf(theta_log[n]);
    float s, co;
    sincosf(th, &s, &co);
    float Lre = mod * co, Lim = mod * s;
    const unsigned* p = Bu + ((size_t)(b * TDIM + c * CHUNK)) * 512 + n;
    float xr = 0.f, xi = 0.f;
#pragma unroll 8
    for (int t = 0; t < CHUNK; ++t) {
        unsigned wv = p[(size_t)t * 512];
        float nr = fmaf(Lre, xr, fmaf(-Lim, xi, bflo(wv)));
        float ni = fmaf(Lre, xi, fmaf(Lim, xr, bfhi(wv)));
        xr = nr; xi = ni;
    }
    carry[(size_t)(b * NCHUNK + c) * 512 + n] = make_float2(xr, xi);
}

__global__ void scan_prefix(const float2* __restrict__ carry, const float* __restrict__ nu_log,
                            const float* __restrict__ theta_log, float2* __restrict__ prefix) {
    int q = blockIdx.x * 256 + threadIdx.x;  // < 8192
    int n = q & 511, b = q >> 9;
    float e = expf(nu_log[n]);
    float modL = expf(-(float)CHUNK * e);
    float th = expf(theta_log[n]);
    double ang = fmod((double)CHUNK * (double)th, 6.283185307179586);
    float s, co;
    sincosf((float)ang, &s, &co);
    float Lre = modL * co, Lim = modL * s;
    float pr = 0.f, pi = 0.f;
    for (int c = 0; c < NCHUNK; ++c) {
        size_t idx = (size_t)(b * NCHUNK + c) * 512 + n;
        prefix[idx] = make_float2(pr, pi);
        float2 ev = carry[idx];
        float nr = fmaf(Lre, pr, fmaf(-Lim, pi, ev.x));
        float ni = fmaf(Lre, pi, fmaf(Lim, pr, ev.y));
        pr = nr; pi = ni;
    }
}

__global__ void scan_apply(const unsigned* __restrict__ Bu, const float* __restrict__ nu_log,
                           const float* __restrict__ theta_log, const float2* __restrict__ prefix,
                           char* __restrict__ Apack) {
    int q = blockIdx.x * 256 + threadIdx.x;
    int n = q & 511, c = (q >> 9) & 63, b = q >> 15;
    float mod = expf(-expf(nu_log[n]));
    float th = expf(theta_log[n]);
    float s, co;
    sincosf(th, &s, &co);
    float Lre = mod * co, Lim = mod * s;
    const unsigned* p = Bu + ((size_t)(b * TDIM + c * CHUNK)) * 512 + n;
    float2 pv = prefix[(size_t)(b * NCHUNK + c) * 512 + n];
    float xr = pv.x, xi = pv.y;
    int kp = (2 * n) & 63;
    int kk = kp >> 5, km = kp & 31;
    int half = km >> 4, gg = (km & 15) >> 2, j = km & 3;
    int cc = (kk << 2) | gg;
    int partial = (n >> 5) * 128 + half * 8 + j * 2;
    int row0 = b * TDIM + c * CHUNK;
#pragma unroll 8
    for (int t = 0; t < CHUNK; ++t) {
        unsigned wv = p[(size_t)t * 512];
        float nr = fmaf(Lre, xr, fmaf(-Lim, xi, bflo(wv)));
        float ni = fmaf(Lre, xi, fmaf(Lim, xr, bfhi(wv)));
        xr = nr; xi = ni;
        int row = row0 + t;
        size_t off = (size_t)row * 3072 + ((cc ^ (row & 7)) << 4) + partial;
        *reinterpret_cast<unsigned*>(Apack + off) =
            (unsigned)f2bf(xr) | ((unsigned)f2bf(xi) << 16);
    }
}

extern "C" void kernel_launch(void* const* d_in, const int* in_sizes, int n_in,
                              void* d_out, int out_size, void* d_ws, size_t ws_size,
                              hipStream_t stream) {
    const float* u         = (const float*)d_in[0];
    const float* nu_log    = (const float*)d_in[1];
    const float* theta_log = (const float*)d_in[2];
    const float* gamma_log = (const float*)d_in[3];
    const float* B_re      = (const float*)d_in[4];
    const float* B_im      = (const float*)d_in[5];
    const float* C_re      = (const float*)d_in[6];
    const float* C_im      = (const float*)d_in[7];
    const float* D         = (const float*)d_in[8];

    char* ws = (char*)d_ws;
    char* Apack = ws;                                   // 65536*3072 B = 201 MB (perm layout)
    size_t off = (size_t)MTOT * 3072;
    char* W1 = ws + off; off += 1024 * 1024;            // 1 MB
    char* W2 = ws + off; off += 512 * 3072;             // 1.5 MB
    float2* carry  = (float2*)(ws + off); off += (size_t)BDIM * NCHUNK * 512 * 8;
    float2* prefix = (float2*)(ws + off); off += (size_t)BDIM * NCHUNK * 512 * 8;

    unsigned short* Bu = (unsigned short*)d_out;  // 65536*1024 ushort == out bytes

    prep_w1<<<dim3(2, 1024), 256, 0, stream>>>(B_re, B_im, gamma_log, W1);
    prep_w2<<<dim3(6, 512), 256, 0, stream>>>(C_re, C_im, D, W2);
    convert_u<<<32768, 256, 0, stream>>>((const float4*)u, Apack);
    // GEMM1: Bu = u_bf16 . W1^T  (M=65536, N=1024, K=512)
    gemm_nt<1, 4, 3072, 1024><<<1024, 512, 0, stream>>>(Apack + 16 * 128, W1, (void*)Bu, 8);
    scan_carry<<<2048, 256, 0, stream>>>((const unsigned*)Bu, nu_log, theta_log, carry);
    scan_prefix<<<32, 256, 0, stream>>>(carry, nu_log, theta_log, prefix);
    scan_apply<<<2048, 256, 0, stream>>>((const unsigned*)Bu, nu_log, theta_log, prefix, Apack);
    // GEMM2: y = Apack . W2^T  (M=65536, N=512, K=1536), f32 out
    gemm_nt<0, 2, 3072, 3072><<<512, 512, 0, stream>>>(Apack, W2, d_out, 24);
}

// Round 12
// 337.887 us; speedup vs baseline: 7.7277x; 7.7277x over previous
//
#include <hip/hip_runtime.h>
#include <hip/hip_bf16.h>
#include <cstdint>
#include <cstddef>

// LRU forward: B=16, T=4096, IN=OUT=N=512
// prep weights (bf16, perm layout) -> convert u -> GEMM1 (Bu; 256^2, B-in-regs
// from L2, A-only LDS, fused chunk-carry) -> prefix -> apply -> GEMM2.
// d_out doubles as scratch for Bu before y overwrites it.
//
// Perm layout: row-major rows; each 64-k tile is 128 B = 8 chunks of 16 B.
// Chunk c at row r holds fragment chunk cc = c ^ (r&7); fragment chunk
// cc = kk*4+g holds k = {kk*32+g*4+j, kk*32+16+g*4+j}. One ds_read_b128 (A via
// LDS) or one global_load_dwordx4 (B direct from L2) = one MFMA fragment.
//
// Register-budget law (r11 lesson): per-SIMD RF = 512 per-wave regs; acc=128
// AGPR => 2 waves/SIMD max => arch cap 128. Single B bank (32 regs) keeps us
// ~100 arch. K-loop: 1 barrier/tile; B(kt+1) issued after last MFMA of kt;
// top vmcnt(4) confirms B (8 older loads), end vmcnt(8) confirms A stages.

using short8 = __attribute__((ext_vector_type(8))) short;
using f32x4 = __attribute__((ext_vector_type(4))) float;

#define BDIM 16
#define TDIM 4096
#define MTOT (BDIM * TDIM)   // 65536
#define CHUNK 64
#define NCHUNK (TDIM / CHUNK) // 64

__device__ __forceinline__ unsigned short f2bf(float f) {
    unsigned u = __float_as_uint(f);
    u = u + 0x7FFFu + ((u >> 16) & 1u);   // RNE
    return (unsigned short)(u >> 16);
}
__device__ __forceinline__ float bflo(unsigned w) { return __uint_as_float(w << 16); }
__device__ __forceinline__ float bfhi(unsigned w) { return __uint_as_float(w & 0xFFFF0000u); }

__device__ __forceinline__ size_t perm_off(int row, int kt, int kp, int rowbytes) {
    int kk = kp >> 5, km = kp & 31;
    int half = km >> 4;
    int g = (km & 15) >> 2, j = km & 3;
    int cc = (kk << 2) | g;
    int c = cc ^ (row & 7);
    return (size_t)row * rowbytes + kt * 128 + (c << 4) + half * 8 + j * 2;
}

__device__ __forceinline__ void gload_lds16(const void* g, void* l) {
    __builtin_amdgcn_global_load_lds((const __attribute__((address_space(1))) void*)g,
                                     (__attribute__((address_space(3))) void*)l, 16, 0, 0);
}

// ---------------- weight prep ----------------
__global__ void prep_w1(const float* __restrict__ B_re, const float* __restrict__ B_im,
                        const float* __restrict__ gamma_log, char* __restrict__ W1) {
    int i = blockIdx.x * 256 + threadIdx.x;  // 0..511 (k)
    int r = blockIdx.y;                      // 0..1023 (row)
    int n = r >> 1;
    float gmm = expf(gamma_log[n]);
    float v = (r & 1) ? B_im[n * 512 + i] * gmm : B_re[n * 512 + i] * gmm;
    *(unsigned short*)(W1 + perm_off(r, i >> 6, i & 63, 1024)) = f2bf(v);
}

__global__ void prep_w2(const float* __restrict__ C_re, const float* __restrict__ C_im,
                        const float* __restrict__ D, char* __restrict__ W2) {
    int k = blockIdx.x * 256 + threadIdx.x;  // 0..1535
    int o = blockIdx.y;                      // 0..511
    float v;
    if (k < 1024) {
        int n = k >> 1;
        v = (k & 1) ? -2.0f * C_im[o * 512 + n] : 2.0f * C_re[o * 512 + n];
    } else {
        v = D[o * 512 + (k - 1024)];
    }
    *(unsigned short*)(W2 + perm_off(o, k >> 6, k & 63, 3072)) = f2bf(v);
}

__global__ void convert_u(const float4* __restrict__ u4, char* __restrict__ Apack) {
    size_t idx = (size_t)blockIdx.x * 256 + threadIdx.x;  // < 65536*128
    float4 v = u4[idx];
    int row = (int)(idx >> 7);
    int c4 = (int)(idx & 127);
    int kg = 1024 + c4 * 4;
    unsigned lo = (unsigned)f2bf(v.x) | ((unsigned)f2bf(v.y) << 16);
    unsigned hi = (unsigned)f2bf(v.z) | ((unsigned)f2bf(v.w) << 16);
    size_t off = perm_off(row, kg >> 6, kg & 63, 3072);
    *reinterpret_cast<uint2*>(Apack + off) = make_uint2(lo, hi);
}

// ---------------- 256x256 MFMA GEMM, B-in-regs (single bank), A-only LDS ------
#define ASM_VMCNT0 asm volatile("s_waitcnt vmcnt(0)" ::: "memory")
#define ASM_VMCNT4 asm volatile("s_waitcnt vmcnt(4)" ::: "memory")
#define ASM_VMCNT8 asm volatile("s_waitcnt vmcnt(8)" ::: "memory")
#define ASM_LGKM0  asm volatile("s_waitcnt lgkmcnt(0)" ::: "memory")
#define ASM_LGKM4  asm volatile("s_waitcnt lgkmcnt(4)" ::: "memory")
#define SCHED0     __builtin_amdgcn_sched_barrier(0)
#define BARRIER    __builtin_amdgcn_s_barrier()
#define PRIO1      __builtin_amdgcn_s_setprio(1)
#define PRIO0      __builtin_amdgcn_s_setprio(0)

template <int OUT_MODE, int NBN, int LDAB, int LDBB>
__global__ __launch_bounds__(512, 2) void gemm_nt(const char* __restrict__ A,
                                                  const char* __restrict__ Bm,
                                                  void* __restrict__ Cout, int ktiles,
                                                  float2* __restrict__ carry,
                                                  const float* __restrict__ nu_log,
                                                  const float* __restrict__ theta_log) {
    __shared__ __align__(16) char lds[131072];  // A dbuf in [0,64K); epilogue uses all
    const int tid = threadIdx.x;
    const int lane = tid & 63, w = tid >> 6;
    const int bid = blockIdx.x;
    const int cpx = gridDim.x >> 3;             // grid divisible by 8
    const int swz = (bid & 7) * cpx + (bid >> 3);
    const int bm = swz / NBN, bn = swz % NBN;
    const int wm = (w >> 2) * 128, wn = (w & 3) * 64;
    const int ml = lane & 15, g = lane >> 4;

    const char* AgrL = A + (size_t)(bm * 256 + w * 16 + (lane >> 3)) * LDAB + (lane & 7) * 16;

#define STG_A(h, kt_, q) do {                                                         \
        const char* s_ = AgrL + (size_t)((h) * 128) * LDAB + (size_t)(kt_) * 128;     \
        char* d_ = lds + (q) * 32768 + (h) * 16384 + w * 2048;                        \
        gload_lds16(s_, d_);                                                          \
        gload_lds16(s_ + (size_t)8 * LDAB, d_ + 1024);                                \
    } while (0)

    // B fragment direct from global (L2-resident weights), perm layout = one 16B chunk
#define LOADB(kt_) do {                                                               \
        _Pragma("unroll") for (int nh = 0; nh < 2; ++nh)                              \
        _Pragma("unroll") for (int ntq = 0; ntq < 2; ++ntq)                           \
        _Pragma("unroll") for (int kk = 0; kk < 2; ++kk) {                            \
            int c_ = bn * 256 + wn + nh * 32 + ntq * 16 + ml;                         \
            bfr[nh][ntq][kk] = *reinterpret_cast<const short8*>(                      \
                Bm + (size_t)c_ * LDBB + (size_t)(kt_) * 128 +                        \
                ((((kk << 2) | g) ^ (ml & 7)) << 4));                                 \
        } } while (0)

#define RD_A1(mh, mt_, Abase) do {                                                    \
        _Pragma("unroll") for (int kk = 0; kk < 2; ++kk) {                            \
            int r_ = wm + (mh) * 64 + (mt_) * 16 + ml;                                \
            int hf_ = r_ >> 7, rl_ = r_ & 127;                                        \
            afr[mt_][kk] = *reinterpret_cast<const short8*>(                          \
                (Abase) + hf_ * 16384 + rl_ * 128 + ((((kk << 2) | g) ^ (rl_ & 7)) << 4)); \
        } } while (0)

    // 16 MFMAs: rows {mtb,mtb+1} of m-half mh, ALL 4 n-fragments (B in regs)
#define MFMA16_MT(mh, mtb)                                                            \
    _Pragma("unroll") for (int kk = 0; kk < 2; ++kk)                                  \
    _Pragma("unroll") for (int mi = 0; mi < 2; ++mi)                                  \
    _Pragma("unroll") for (int nh = 0; nh < 2; ++nh)                                  \
    _Pragma("unroll") for (int nt = 0; nt < 2; ++nt)                                  \
        acc[(mh) * 4 + (mtb) + mi][nh * 2 + nt] = __builtin_amdgcn_mfma_f32_16x16x32_bf16( \
            afr[(mtb) + mi][kk], bfr[nh][nt][kk], acc[(mh) * 4 + (mtb) + mi][nh * 2 + nt], 0, 0, 0)

    f32x4 acc[8][4] = {};
    short8 afr[4][2];
    short8 bfr[2][2][2];

    // prologue: A(0) stages FIRST (so prologue vmcnt(8) drains them), then B(0)
    STG_A(0, 0, 0); STG_A(1, 0, 0);
    LOADB(0);
    ASM_VMCNT8;   // A(0) staged (self); B(0) 8 loads still in flight
    BARRIER;      // cross-wave: A(0) staged
    SCHED0;

    for (int kt = 0; kt < ktiles; ++kt) {
        const int cur = kt & 1, nq = cur ^ 1;
        const char* Ab = lds + cur * 32768;
        const bool more = (kt + 1 < ktiles);
        // top: stage next A, then confirm B(kt) (the 8 oldest loads)
        if (more) {
            STG_A(0, kt + 1, nq); STG_A(1, kt + 1, nq);
            ASM_VMCNT4;
        } else {
            ASM_VMCNT0;
        }
        SCHED0;
        // m-half 0
        RD_A1(0, 0, Ab); RD_A1(0, 1, Ab);
        SCHED0;
        RD_A1(0, 2, Ab); RD_A1(0, 3, Ab);
        ASM_LGKM4; SCHED0;
        PRIO1; MFMA16_MT(0, 0); PRIO0;
        ASM_LGKM0; SCHED0;
        PRIO1; MFMA16_MT(0, 2); PRIO0;
        // m-half 1
        RD_A1(1, 0, Ab); RD_A1(1, 1, Ab);
        SCHED0;
        RD_A1(1, 2, Ab); RD_A1(1, 3, Ab);
        ASM_LGKM4; SCHED0;
        PRIO1; MFMA16_MT(1, 0); PRIO0;
        ASM_LGKM0; SCHED0;
        PRIO1; MFMA16_MT(1, 2); PRIO0;
        // B fully consumed: prefetch next tile's B into the same bank (WAR-safe
        // in program order); vmcnt(8) then drains the 4 older A stages.
        if (more) {
            LOADB(kt + 1);
            ASM_VMCNT8;
        }
        BARRIER;
        SCHED0;
    }

    // ---------------- epilogue ----------------
    if (OUT_MODE == 0) {
        float* O = (float*)Cout;
#pragma unroll
        for (int mt = 0; mt < 8; ++mt)
#pragma unroll
            for (int nt = 0; nt < 4; ++nt)
#pragma unroll
                for (int r_ = 0; r_ < 4; ++r_) {
                    int grow = bm * 256 + wm + mt * 16 + g * 4 + r_;
                    int gcol = bn * 256 + wn + nt * 16 + ml;
                    O[(size_t)grow * 512 + gcol] = acc[mt][nt][r_];
                }
    } else {
        // r6-verified fused carry: write Bu + dump 256x256 bf16 tile to LDS
        unsigned short* BuOut = (unsigned short*)Cout;
#pragma unroll
        for (int mt = 0; mt < 8; ++mt)
#pragma unroll
            for (int nt = 0; nt < 4; ++nt)
#pragma unroll
                for (int r_ = 0; r_ < 4; ++r_) {
                    int lrow = wm + mt * 16 + g * 4 + r_;
                    int lcol = wn + nt * 16 + ml;
                    unsigned short hv = f2bf(acc[mt][nt][r_]);
                    *(unsigned short*)(lds + lrow * 512 + lcol * 2) = hv;
                    BuOut[(size_t)(bm * 256 + lrow) * 1024 + bn * 256 + lcol] = hv;
                }
        ASM_LGKM0;
        BARRIER;
        SCHED0;
        // 512 chains: 4 local chunks x 128 n-pairs
        int n_local = tid & 127, c_local = tid >> 7;
        int nglob = bn * 128 + n_local;
        float mod = expf(-expf(nu_log[nglob]));
        float th = expf(theta_log[nglob]);
        float s, co;
        sincosf(th, &s, &co);
        float Lre = mod * co, Lim = mod * s;
        const char* base = lds + (c_local * 64) * 512 + n_local * 4;
        float xr = 0.f, xi = 0.f;
#pragma unroll 8
        for (int t = 0; t < 64; ++t) {
            unsigned wv = *reinterpret_cast<const unsigned*>(base + t * 512);
            float nr = fmaf(Lre, xr, fmaf(-Lim, xi, bflo(wv)));
            float ni = fmaf(Lre, xi, fmaf(Lim, xr, bfhi(wv)));
            xr = nr; xi = ni;
        }
        int b = (bm * 256) >> 12;
        int cglob = (((bm * 256) & 4095) >> 6) + c_local;
        carry[(size_t)(b * NCHUNK + cglob) * 512 + nglob] = make_float2(xr, xi);
    }
#undef STG_A
#undef LOADB
#undef RD_A1
#undef MFMA16_MT
}

// ---------------- scan (prefix over chunk carries, then apply) ----------------
__global__ void scan_prefix(const float2* __restrict__ carry, const float* __restrict__ nu_log,
                            const float* __restrict__ theta_log, float2* __restrict__ prefix) {
    int q = blockIdx.x * 256 + threadIdx.x;  // < 8192
    int n = q & 511, b = q >> 9;
    float e = expf(nu_log[n]);
    float modL = expf(-(float)CHUNK * e);
    float th = expf(theta_log[n]);
    double ang = fmod((double)CHUNK * (double)th, 6.283185307179586);
    float s, co;
    sincosf((float)ang, &s, &co);
    float Lre = modL * co, Lim = modL * s;
    float pr = 0.f, pi = 0.f;
    for (int c = 0; c < NCHUNK; ++c) {
        size_t idx = (size_t)(b * NCHUNK + c) * 512 + n;
        prefix[idx] = make_float2(pr, pi);
        float2 ev = carry[idx];
        float nr = fmaf(Lre, pr, fmaf(-Lim, pi, ev.x));
        float ni = fmaf(Lre, pi, fmaf(Lim, pr, ev.y));
        pr = nr; pi = ni;
    }
}

__global__ void scan_apply(const unsigned* __restrict__ Bu, const float* __restrict__ nu_log,
                           const float* __restrict__ theta_log, const float2* __restrict__ prefix,
                           char* __restrict__ Apack) {
    int q = blockIdx.x * 256 + threadIdx.x;
    int n = q & 511, c = (q >> 9) & 63, b = q >> 15;
    float mod = expf(-expf(nu_log[n]));
    float th = expf(theta_log[n]);
    float s, co;
    sincosf(th, &s, &co);
    float Lre = mod * co, Lim = mod * s;
    const unsigned* p = Bu + ((size_t)(b * TDIM + c * CHUNK)) * 512 + n;
    float2 pv = prefix[(size_t)(b * NCHUNK + c) * 512 + n];
    float xr = pv.x, xi = pv.y;
    int kp = (2 * n) & 63;
    int kk = kp >> 5, km = kp & 31;
    int half = km >> 4, gg = (km & 15) >> 2, j = km & 3;
    int cc = (kk << 2) | gg;
    int partial = (n >> 5) * 128 + half * 8 + j * 2;
    int row0 = b * TDIM + c * CHUNK;
#pragma unroll 8
    for (int t = 0; t < CHUNK; ++t) {
        unsigned wv = p[(size_t)t * 512];
        float nr = fmaf(Lre, xr, fmaf(-Lim, xi, bflo(wv)));
        float ni = fmaf(Lre, xi, fmaf(Lim, xr, bfhi(wv)));
        xr = nr; xi = ni;
        int row = row0 + t;
        size_t off = (size_t)row * 3072 + ((cc ^ (row & 7)) << 4) + partial;
        *reinterpret_cast<unsigned*>(Apack + off) =
            (unsigned)f2bf(xr) | ((unsigned)f2bf(xi) << 16);
    }
}

extern "C" void kernel_launch(void* const* d_in, const int* in_sizes, int n_in,
                              void* d_out, int out_size, void* d_ws, size_t ws_size,
                              hipStream_t stream) {
    const float* u         = (const float*)d_in[0];
    const float* nu_log    = (const float*)d_in[1];
    const float* theta_log = (const float*)d_in[2];
    const float* gamma_log = (const float*)d_in[3];
    const float* B_re      = (const float*)d_in[4];
    const float* B_im      = (const float*)d_in[5];
    const float* C_re      = (const float*)d_in[6];
    const float* C_im      = (const float*)d_in[7];
    const float* D         = (const float*)d_in[8];

    char* ws = (char*)d_ws;
    char* Apack = ws;                                   // 65536*3072 B = 201 MB (perm layout)
    size_t off = (size_t)MTOT * 3072;
    char* W1 = ws + off; off += 1024 * 1024;            // 1 MB
    char* W2 = ws + off; off += 512 * 3072;             // 1.5 MB
    float2* carry  = (float2*)(ws + off); off += (size_t)BDIM * NCHUNK * 512 * 8;
    float2* prefix = (float2*)(ws + off); off += (size_t)BDIM * NCHUNK * 512 * 8;

    unsigned short* Bu = (unsigned short*)d_out;  // 65536*1024 ushort == out bytes

    prep_w1<<<dim3(2, 1024), 256, 0, stream>>>(B_re, B_im, gamma_log, W1);
    prep_w2<<<dim3(6, 512), 256, 0, stream>>>(C_re, C_im, D, W2);
    convert_u<<<32768, 256, 0, stream>>>((const float4*)u, Apack);
    // GEMM1: Bu = u_bf16 . W1^T  (M=65536, N=1024, K=512) + fused chunk-carry
    gemm_nt<1, 4, 3072, 1024><<<1024, 512, 0, stream>>>(Apack + 16 * 128, W1,
                                                        (void*)Bu, 8, carry, nu_log, theta_log);
    scan_prefix<<<32, 256, 0, stream>>>(carry, nu_log, theta_log, prefix);
    scan_apply<<<2048, 256, 0, stream>>>((const unsigned*)Bu, nu_log, theta_log, prefix, Apack);
    // GEMM2: y = Apack . W2^T  (M=65536, N=512, K=1536), f32 out
    gemm_nt<0, 2, 3072, 3072><<<512, 512, 0, stream>>>(Apack, W2, d_out, 24,
                                                       nullptr, nullptr, nullptr);
}

// Round 13
// 299.988 us; speedup vs baseline: 8.7040x; 1.1263x over previous
//
#include <hip/hip_runtime.h>
#include <hip/hip_bf16.h>
#include <cstdint>
#include <cstddef>

// LRU forward: B=16, T=4096, IN=OUT=N=512
// prep weights (bf16, perm layout) -> convert u -> GEMM1 (Bu, 256^2 8-phase
// deep-counted pipeline, carry fused in epilogue) -> prefix -> apply -> GEMM2.
// d_out doubles as scratch for Bu before y overwrites it.
//
// Perm layout: row-major rows; each 64-k tile is 128 B = 8 chunks of 16 B.
// Chunk c at row r holds fragment chunk cc = c ^ (r&7); fragment chunk
// cc = kk*4+g holds k = {kk*32+g*4+j, kk*32+16+g*4+j}. One ds_read_b128 = one
// MFMA fragment, conflict-free; global_load_lds staging stays linear.
//
// K-loop (8 phases / 2 K-tiles, ONE barrier per phase):
//  P1/P5: read ALL B (8) + A-bank0 (8) of cur tile; lgkm4 -> MFMA(m0,n0); lgkm0
//  P2/P6: read-free: MFMA(m0,n1) from regs (overlaps other waves' DS drain)
//  P3/P7: read A-bank1 (8); lgkm0 -> MFMA(m1,n0)
//  P4/P8: read-free: vmcnt(4) pre-barrier confirms next tile; MFMA(m1,n1)
// Stages (2 gloads) issued AFTER each phase's barrier (slot's readers drained
// by that slot's read-phase trailing lgkm0, >=1 barrier before the stage):
//  P1:t1.A1  P2:t2.B0  P3:t2.B1  P4:t2.A0  P5:t2.A1  P6:t3.B0  P7:t3.B1  P8:t3.A0
// In-flight: 6 -> P4 vmcnt(4) [newest waited half staged 3 phases ago] -> 4+...

using short8 = __attribute__((ext_vector_type(8))) short;
using f32x4 = __attribute__((ext_vector_type(4))) float;

#define BDIM 16
#define TDIM 4096
#define MTOT (BDIM * TDIM)   // 65536
#define CHUNK 64
#define NCHUNK (TDIM / CHUNK) // 64

__device__ __forceinline__ unsigned short f2bf(float f) {
    unsigned u = __float_as_uint(f);
    u = u + 0x7FFFu + ((u >> 16) & 1u);   // RNE
    return (unsigned short)(u >> 16);
}
__device__ __forceinline__ float bflo(unsigned w) { return __uint_as_float(w << 16); }
__device__ __forceinline__ float bfhi(unsigned w) { return __uint_as_float(w & 0xFFFF0000u); }

__device__ __forceinline__ size_t perm_off(int row, int kt, int kp, int rowbytes) {
    int kk = kp >> 5, km = kp & 31;
    int half = km >> 4;
    int g = (km & 15) >> 2, j = km & 3;
    int cc = (kk << 2) | g;
    int c = cc ^ (row & 7);
    return (size_t)row * rowbytes + kt * 128 + (c << 4) + half * 8 + j * 2;
}

__device__ __forceinline__ void gload_lds16(const void* g, void* l) {
    __builtin_amdgcn_global_load_lds((const __attribute__((address_space(1))) void*)g,
                                     (__attribute__((address_space(3))) void*)l, 16, 0, 0);
}

// ---------------- weight prep ----------------
__global__ void prep_w1(const float* __restrict__ B_re, const float* __restrict__ B_im,
                        const float* __restrict__ gamma_log, char* __restrict__ W1) {
    int i = blockIdx.x * 256 + threadIdx.x;  // 0..511 (k)
    int r = blockIdx.y;                      // 0..1023 (row)
    int n = r >> 1;
    float gmm = expf(gamma_log[n]);
    float v = (r & 1) ? B_im[n * 512 + i] * gmm : B_re[n * 512 + i] * gmm;
    *(unsigned short*)(W1 + perm_off(r, i >> 6, i & 63, 1024)) = f2bf(v);
}

__global__ void prep_w2(const float* __restrict__ C_re, const float* __restrict__ C_im,
                        const float* __restrict__ D, char* __restrict__ W2) {
    int k = blockIdx.x * 256 + threadIdx.x;  // 0..1535
    int o = blockIdx.y;                      // 0..511
    float v;
    if (k < 1024) {
        int n = k >> 1;
        v = (k & 1) ? -2.0f * C_im[o * 512 + n] : 2.0f * C_re[o * 512 + n];
    } else {
        v = D[o * 512 + (k - 1024)];
    }
    *(unsigned short*)(W2 + perm_off(o, k >> 6, k & 63, 3072)) = f2bf(v);
}

__global__ void convert_u(const float4* __restrict__ u4, char* __restrict__ Apack) {
    size_t idx = (size_t)blockIdx.x * 256 + threadIdx.x;  // < 65536*128
    float4 v = u4[idx];
    int row = (int)(idx >> 7);
    int c4 = (int)(idx & 127);
    int kg = 1024 + c4 * 4;
    unsigned lo = (unsigned)f2bf(v.x) | ((unsigned)f2bf(v.y) << 16);
    unsigned hi = (unsigned)f2bf(v.z) | ((unsigned)f2bf(v.w) << 16);
    size_t off = perm_off(row, kg >> 6, kg & 63, 3072);
    *reinterpret_cast<uint2*>(Apack + off) = make_uint2(lo, hi);
}

// ---------------- 256x256 8-phase deep-counted MFMA GEMM (NT, perm layout) ----
#define ASM_VMCNT0 asm volatile("s_waitcnt vmcnt(0)" ::: "memory")
#define ASM_VMCNT4 asm volatile("s_waitcnt vmcnt(4)" ::: "memory")
#define ASM_VMCNT6 asm volatile("s_waitcnt vmcnt(6)" ::: "memory")
#define ASM_LGKM0  asm volatile("s_waitcnt lgkmcnt(0)" ::: "memory")
#define ASM_LGKM4  asm volatile("s_waitcnt lgkmcnt(4)" ::: "memory")
#define SCHED0     __builtin_amdgcn_sched_barrier(0)
#define BARRIER    __builtin_amdgcn_s_barrier()
#define PRIO1      __builtin_amdgcn_s_setprio(1)
#define PRIO0      __builtin_amdgcn_s_setprio(0)

template <int OUT_MODE, int NBN, int LDAB, int LDBB>
__global__ __launch_bounds__(512, 2) void gemm_nt(const char* __restrict__ A,
                                                  const char* __restrict__ Bm,
                                                  void* __restrict__ Cout, int ktiles,
                                                  float2* __restrict__ carry,
                                                  const float* __restrict__ nu_log,
                                                  const float* __restrict__ theta_log) {
    __shared__ __align__(16) char lds[131072];
    const int tid = threadIdx.x;
    const int lane = tid & 63, w = tid >> 6;
    const int bid = blockIdx.x;
    const int cpx = gridDim.x >> 3;             // grid divisible by 8
    const int swz = (bid & 7) * cpx + (bid >> 3);
    const int bm = swz / NBN, bn = swz % NBN;
    const int wm = (w >> 2) * 128, wn = (w & 3) * 64;
    const int ml = lane & 15, g = lane >> 4;

    const char* AgrL = A + (size_t)(bm * 256 + w * 16 + (lane >> 3)) * LDAB + (lane & 7) * 16;
    const char* BgrL = Bm + (size_t)(bn * 256 + w * 16 + (lane >> 3)) * LDBB + (lane & 7) * 16;

#define STG_A(h, kt_, q) do {                                                         \
        const char* s_ = AgrL + (size_t)((h) * 128) * LDAB + (size_t)(kt_) * 128;     \
        char* d_ = lds + (q) * 65536 + (h) * 16384 + w * 2048;                        \
        gload_lds16(s_, d_);                                                          \
        gload_lds16(s_ + (size_t)8 * LDAB, d_ + 1024);                                \
    } while (0)
#define STG_B(h, kt_, q) do {                                                         \
        const char* s_ = BgrL + (size_t)((h) * 128) * LDBB + (size_t)(kt_) * 128;     \
        char* d_ = lds + (q) * 65536 + 32768 + (h) * 16384 + w * 2048;                \
        gload_lds16(s_, d_);                                                          \
        gload_lds16(s_ + (size_t)8 * LDBB, d_ + 1024);                                \
    } while (0)

#define RD_A_(bank, Abase) do {                                                       \
        _Pragma("unroll") for (int mt = 0; mt < 4; ++mt)                              \
        _Pragma("unroll") for (int kk = 0; kk < 2; ++kk) {                            \
            int r_ = wm + (bank) * 64 + mt * 16 + ml;                                 \
            int hf_ = r_ >> 7, rl_ = r_ & 127;                                        \
            afr[mt][kk] = *reinterpret_cast<const short8*>(                           \
                (Abase) + hf_ * 16384 + rl_ * 128 + ((((kk << 2) | g) ^ (rl_ & 7)) << 4)); \
        } } while (0)
#define RD_B_(nh, Bbase) do {                                                         \
        _Pragma("unroll") for (int nt = 0; nt < 2; ++nt)                              \
        _Pragma("unroll") for (int kk = 0; kk < 2; ++kk) {                            \
            int c_ = wn + (nh) * 32 + nt * 16 + ml;                                   \
            int hf_ = c_ >> 7, cl_ = c_ & 127;                                        \
            bfr[nh][nt][kk] = *reinterpret_cast<const short8*>(                       \
                (Bbase) + hf_ * 16384 + cl_ * 128 + ((((kk << 2) | g) ^ (cl_ & 7)) << 4)); \
        } } while (0)

#define MFMA16(mh, nh)                                                                \
    _Pragma("unroll") for (int kk = 0; kk < 2; ++kk)                                  \
    _Pragma("unroll") for (int mt = 0; mt < 4; ++mt)                                  \
    _Pragma("unroll") for (int nt = 0; nt < 2; ++nt)                                  \
        acc[(mh) * 4 + mt][(nh) * 2 + nt] = __builtin_amdgcn_mfma_f32_16x16x32_bf16(  \
            afr[mt][kk], bfr[nh][nt][kk], acc[(mh) * 4 + mt][(nh) * 2 + nt], 0, 0, 0)

    f32x4 acc[8][4] = {};
    short8 afr[4][2];
    short8 bfr[2][2][2];

    const char* A0b = lds;
    const char* B0b = lds + 32768;
    const char* A1b = lds + 65536;
    const char* B1b = lds + 98304;

    // prologue: t0 full (8 loads) + t1.B0,B1,A0 (6 loads); confirm t0 only.
    STG_B(0, 0, 0); STG_B(1, 0, 0); STG_A(0, 0, 0); STG_A(1, 0, 0);
    STG_B(0, 1, 1); STG_B(1, 1, 1); STG_A(0, 1, 1);
    ASM_VMCNT6;   // t0's 8 loads done (self)
    BARRIER;      // cross-wave: t0 staged
    SCHED0;

    const int NT = ktiles >> 1;
    for (int it = 0; it < NT; ++it) {
        const int t1i = 2 * it + 1, t2i = 2 * it + 2, t3i = 2 * it + 3;
        const bool more = (it + 1 < NT);
        // ---- P1: reads all-B + A-bank0 (buf0); stage t1.A1; MFMA(0,0)
        RD_B_(0, B0b); RD_A_(0, A0b);
        SCHED0;
        RD_B_(1, B0b);
        BARRIER; SCHED0;
        STG_A(1, t1i, 1);
        ASM_LGKM4; SCHED0;               // bfr0 + afr bank0 confirmed
        PRIO1; MFMA16(0, 0); PRIO0;
        ASM_LGKM0;                       // bfr1 drained -> B slots free
        // ---- P2: read-free; stage t2.B0; MFMA(0,1)
        BARRIER; SCHED0;
        if (more) STG_B(0, t2i, 0);
        PRIO1; MFMA16(0, 1); PRIO0;
        // ---- P3: reads A-bank1; stage t2.B1; MFMA(1,0)
        RD_A_(1, A0b);
        BARRIER; SCHED0;
        if (more) STG_B(1, t2i, 0);
        ASM_LGKM0; SCHED0;
        PRIO1; MFMA16(1, 0); PRIO0;
        // ---- P4: read-free; confirm t1 (vmcnt pre-barrier); stage t2.A0; MFMA(1,1)
        if (more) { ASM_VMCNT4; } else { ASM_VMCNT0; }
        BARRIER; SCHED0;                 // cross-wave: t1 staged
        if (more) STG_A(0, t2i, 0);
        PRIO1; MFMA16(1, 1); PRIO0;
        // ---- P5: reads all-B + A-bank0 (buf1); stage t2.A1; MFMA(0,0)
        RD_B_(0, B1b); RD_A_(0, A1b);
        SCHED0;
        RD_B_(1, B1b);
        BARRIER; SCHED0;
        if (more) STG_A(1, t2i, 0);
        ASM_LGKM4; SCHED0;
        PRIO1; MFMA16(0, 0); PRIO0;
        ASM_LGKM0;
        // ---- P6: read-free; stage t3.B0; MFMA(0,1)
        BARRIER; SCHED0;
        if (more) STG_B(0, t3i, 1);
        PRIO1; MFMA16(0, 1); PRIO0;
        // ---- P7: reads A-bank1; stage t3.B1; MFMA(1,0)
        RD_A_(1, A1b);
        BARRIER; SCHED0;
        if (more) STG_B(1, t3i, 1);
        ASM_LGKM0; SCHED0;
        PRIO1; MFMA16(1, 0); PRIO0;
        // ---- P8: read-free; confirm t2; stage t3.A0; MFMA(1,1)
        if (more) { ASM_VMCNT4; }
        BARRIER; SCHED0;                 // cross-wave: t2 staged (when more)
        if (more) STG_A(0, t3i, 1);
        PRIO1; MFMA16(1, 1); PRIO0;
    }

    // ---------------- epilogue ----------------
    if (OUT_MODE == 0) {
        float* O = (float*)Cout;
#pragma unroll
        for (int mt = 0; mt < 8; ++mt)
#pragma unroll
            for (int nt = 0; nt < 4; ++nt)
#pragma unroll
                for (int r_ = 0; r_ < 4; ++r_) {
                    int grow = bm * 256 + wm + mt * 16 + g * 4 + r_;
                    int gcol = bn * 256 + wn + nt * 16 + ml;
                    O[(size_t)grow * 512 + gcol] = acc[mt][nt][r_];
                }
    } else {
        // write Bu (bf16, packed cols) + dump tile to LDS for fused chunk-carry
        unsigned short* BuOut = (unsigned short*)Cout;
        BARRIER;   // all waves past P7's reads (trailing lgkm0) before LDS reuse
#pragma unroll
        for (int mt = 0; mt < 8; ++mt)
#pragma unroll
            for (int nt = 0; nt < 4; ++nt)
#pragma unroll
                for (int r_ = 0; r_ < 4; ++r_) {
                    int lrow = wm + mt * 16 + g * 4 + r_;
                    int lcol = wn + nt * 16 + ml;
                    unsigned short hv = f2bf(acc[mt][nt][r_]);
                    *(unsigned short*)(lds + lrow * 512 + lcol * 2) = hv;
                    BuOut[(size_t)(bm * 256 + lrow) * 1024 + bn * 256 + lcol] = hv;
                }
        ASM_LGKM0;
        BARRIER;
        SCHED0;
        // 512 chains: 4 local chunks x 128 n-pairs
        int n_local = tid & 127, c_local = tid >> 7;
        int nglob = bn * 128 + n_local;
        float mod = expf(-expf(nu_log[nglob]));
        float th = expf(theta_log[nglob]);
        float s, co;
        sincosf(th, &s, &co);
        float Lre = mod * co, Lim = mod * s;
        const char* base = lds + (c_local * 64) * 512 + n_local * 4;
        float xr = 0.f, xi = 0.f;
#pragma unroll 8
        for (int t = 0; t < 64; ++t) {
            unsigned wv = *reinterpret_cast<const unsigned*>(base + t * 512);
            float nr = fmaf(Lre, xr, fmaf(-Lim, xi, bflo(wv)));
            float ni = fmaf(Lre, xi, fmaf(Lim, xr, bfhi(wv)));
            xr = nr; xi = ni;
        }
        int b = (bm * 256) >> 12;
        int cglob = (((bm * 256) & 4095) >> 6) + c_local;
        carry[(size_t)(b * NCHUNK + cglob) * 512 + nglob] = make_float2(xr, xi);
    }
#undef STG_A
#undef STG_B
#undef RD_A_
#undef RD_B_
#undef MFMA16
}

// ---------------- scan (prefix over chunk carries, then apply) ----------------
__global__ void scan_prefix(const float2* __restrict__ carry, const float* __restrict__ nu_log,
                            const float* __restrict__ theta_log, float2* __restrict__ prefix) {
    int q = blockIdx.x * 256 + threadIdx.x;  // < 8192
    int n = q & 511, b = q >> 9;
    float e = expf(nu_log[n]);
    float modL = expf(-(float)CHUNK * e);
    float th = expf(theta_log[n]);
    double ang = fmod((double)CHUNK * (double)th, 6.283185307179586);
    float s, co;
    sincosf((float)ang, &s, &co);
    float Lre = modL * co, Lim = modL * s;
    float pr = 0.f, pi = 0.f;
    for (int c = 0; c < NCHUNK; ++c) {
        size_t idx = (size_t)(b * NCHUNK + c) * 512 + n;
        prefix[idx] = make_float2(pr, pi);
        float2 ev = carry[idx];
        float nr = fmaf(Lre, pr, fmaf(-Lim, pi, ev.x));
        float ni = fmaf(Lre, pi, fmaf(Lim, pr, ev.y));
        pr = nr; pi = ni;
    }
}

__global__ void scan_apply(const unsigned* __restrict__ Bu, const float* __restrict__ nu_log,
                           const float* __restrict__ theta_log, const float2* __restrict__ prefix,
                           char* __restrict__ Apack) {
    int q = blockIdx.x * 256 + threadIdx.x;
    int n = q & 511, c = (q >> 9) & 63, b = q >> 15;
    float mod = expf(-expf(nu_log[n]));
    float th = expf(theta_log[n]);
    float s, co;
    sincosf(th, &s, &co);
    float Lre = mod * co, Lim = mod * s;
    const unsigned* p = Bu + ((size_t)(b * TDIM + c * CHUNK)) * 512 + n;
    float2 pv = prefix[(size_t)(b * NCHUNK + c) * 512 + n];
    float xr = pv.x, xi = pv.y;
    int kp = (2 * n) & 63;
    int kk = kp >> 5, km = kp & 31;
    int half = km >> 4, gg = (km & 15) >> 2, j = km & 3;
    int cc = (kk << 2) | gg;
    int partial = (n >> 5) * 128 + half * 8 + j * 2;
    int row0 = b * TDIM + c * CHUNK;
#pragma unroll 8
    for (int t = 0; t < CHUNK; ++t) {
        unsigned wv = p[(size_t)t * 512];
        float nr = fmaf(Lre, xr, fmaf(-Lim, xi, bflo(wv)));
        float ni = fmaf(Lre, xi, fmaf(Lim, xr, bfhi(wv)));
        xr = nr; xi = ni;
        int row = row0 + t;
        size_t off = (size_t)row * 3072 + ((cc ^ (row & 7)) << 4) + partial;
        *reinterpret_cast<unsigned*>(Apack + off) =
            (unsigned)f2bf(xr) | ((unsigned)f2bf(xi) << 16);
    }
}

extern "C" void kernel_launch(void* const* d_in, const int* in_sizes, int n_in,
                              void* d_out, int out_size, void* d_ws, size_t ws_size,
                              hipStream_t stream) {
    const float* u         = (const float*)d_in[0];
    const float* nu_log    = (const float*)d_in[1];
    const float* theta_log = (const float*)d_in[2];
    const float* gamma_log = (const float*)d_in[3];
    const float* B_re      = (const float*)d_in[4];
    const float* B_im      = (const float*)d_in[5];
    const float* C_re      = (const float*)d_in[6];
    const float* C_im      = (const float*)d_in[7];
    const float* D         = (const float*)d_in[8];

    char* ws = (char*)d_ws;
    char* Apack = ws;                                   // 65536*3072 B = 201 MB (perm layout)
    size_t off = (size_t)MTOT * 3072;
    char* W1 = ws + off; off += 1024 * 1024;            // 1 MB
    char* W2 = ws + off; off += 512 * 3072;             // 1.5 MB
    float2* carry  = (float2*)(ws + off); off += (size_t)BDIM * NCHUNK * 512 * 8;
    float2* prefix = (float2*)(ws + off); off += (size_t)BDIM * NCHUNK * 512 * 8;

    unsigned short* Bu = (unsigned short*)d_out;  // 65536*1024 ushort == out bytes

    prep_w1<<<dim3(2, 1024), 256, 0, stream>>>(B_re, B_im, gamma_log, W1);
    prep_w2<<<dim3(6, 512), 256, 0, stream>>>(C_re, C_im, D, W2);
    convert_u<<<32768, 256, 0, stream>>>((const float4*)u, Apack);
    // GEMM1: Bu = u_bf16 . W1^T  (M=65536, N=1024, K=512) + fused chunk-carry
    gemm_nt<1, 4, 3072, 1024><<<1024, 512, 0, stream>>>(Apack + 16 * 128, W1,
                                                        (void*)Bu, 8, carry, nu_log, theta_log);
    scan_prefix<<<32, 256, 0, stream>>>(carry, nu_log, theta_log, prefix);
    scan_apply<<<2048, 256, 0, stream>>>((const unsigned*)Bu, nu_log, theta_log, prefix, Apack);
    // GEMM2: y = Apack . W2^T  (M=65536, N=512, K=1536), f32 out
    gemm_nt<0, 2, 3072, 3072><<<512, 512, 0, stream>>>(Apack, W2, d_out, 24,
                                                       nullptr, nullptr, nullptr);
}